// Round 5
// baseline (130.662 us; speedup 1.0000x reference)
//
#include <hip/hip_runtime.h>

// MLP: 64 × (Linear(5,5)+ReLU) then Linear(5,1), BATCH = 1048576 rows.
// fp32 VALU compute-bound. R5: FORCE v_pk_fma_f32 with SGPR-pair weight
// operand via inline asm ("s" constraint on 64-bit duplicated pair).
//
// R4 post-mortem: compiler never folds uniform loads into VOP3P scalar
// operands — it splats every weight into a VGPR pair (2 movs each),
// ~81 instr/layer instead of 35. Inline asm pins the selection:
//   v_pk_fma_f32 acc, h(v), w(s[2n:2n+1]), acc     (1 SGPR read: legal)
//   v_pk_mul_f32 acc, ones(v), bias(s)             (bias init, 1 instr)
// Weight pairs come from the prep kernel (d_ws), 30 consecutive u64 per
// layer -> s_load_dwordx16 batches on the scalar pipe, hidden by 8 w/SIMD.
// Per layer per thread (2 rows): 5 mul + 25 fma + 5 max = 35 VALU instr.

#define MLP_DEPTH 64
#define MLP_D 5

typedef float f2 __attribute__((ext_vector_type(2)));

// acc = a * w + acc   (a: VGPR pair, w: SGPR pair)
#define PK_FMA_S(acc, a, w) \
    asm("v_pk_fma_f32 %0, %1, %2, %0" : "+v"(acc) : "v"(a), "s"(w))
// acc = a * w         (bias splat: a = (1,1), w = (b,b) SGPR pair)
#define PK_MUL_S(acc, a, w) \
    asm("v_pk_mul_f32 %0, %1, %2" : "=v"(acc) : "v"(a), "s"(w))

// d_ws layout: per layer l, 30 u64 pairs: W[j*5+i] (j-major, 25) then b[j] (5);
// then W_out pairs (5) and b_out pair (1).
__global__ __launch_bounds__(256) void MLP_prep_kernel(
    const float* __restrict__ Ws, const float* __restrict__ bs,
    const float* __restrict__ W_out, const float* __restrict__ b_out,
    float* __restrict__ ws)
{
    const int idx = blockIdx.x * blockDim.x + threadIdx.x;
    const int npairs_layers = MLP_DEPTH * 30;
    if (idx < npairs_layers) {
        const int l = idx / 30, k = idx % 30;
        const float v = (k < 25) ? Ws[l * 25 + k] : bs[l * MLP_D + (k - 25)];
        ws[2 * idx + 0] = v;
        ws[2 * idx + 1] = v;
    } else if (idx < npairs_layers + 6) {
        const int k = idx - npairs_layers;
        const float v = (k < MLP_D) ? W_out[k] : b_out[0];
        ws[2 * idx + 0] = v;
        ws[2 * idx + 1] = v;
    }
}

__global__ __launch_bounds__(256) void MLP_89687507075104_kernel(
    const float* __restrict__ x,                    // [n, 5]
    const unsigned long long* __restrict__ wdup,    // duplicated pairs (u64)
    float* __restrict__ out,                        // [n]
    int n)
{
    const int t = blockIdx.x * blockDim.x + threadIdx.x;
    const long row0 = (long)t * 2;
    if (row0 >= n) return;

    // 10 contiguous floats = rows row0,row0+1 (8B-aligned f2 loads).
    const f2* xp = reinterpret_cast<const f2*>(x + row0 * MLP_D);
    const f2 v0 = xp[0], v1 = xp[1], v2 = xp[2], v3 = xp[3], v4 = xp[4];
    // h[i] = (row0[i], row1[i])
    f2 h[MLP_D];
    h[0] = (f2){ v0.x, v2.y };
    h[1] = (f2){ v0.y, v3.x };
    h[2] = (f2){ v1.x, v3.y };
    h[3] = (f2){ v1.y, v4.x };
    h[4] = (f2){ v2.x, v4.y };

    const f2 ones = (f2){ 1.0f, 1.0f };

#pragma unroll
    for (int l = 0; l < MLP_DEPTH; ++l) {
        const unsigned long long* wp = wdup + l * 30;  // wave-uniform
        f2 a[MLP_D];
#pragma unroll
        for (int j = 0; j < MLP_D; ++j) {
            const unsigned long long bj = wp[25 + j];
            PK_MUL_S(a[j], ones, bj);              // a[j] = (b,b)
        }
#pragma unroll
        for (int i = 0; i < MLP_D; ++i) {
#pragma unroll
            for (int j = 0; j < MLP_D; ++j) {
                const unsigned long long w = wp[j * MLP_D + i];
                PK_FMA_S(a[j], h[i], w);           // a[j] += h[i]*w
            }
        }
#pragma unroll
        for (int j = 0; j < MLP_D; ++j)
            h[j] = __builtin_elementwise_max(a[j], (f2)0.0f);  // v_pk_max_f32
    }

    // Output layer: Linear(5,1) for both rows.
    const unsigned long long* wo = wdup + MLP_DEPTH * 30;
    f2 o;
    PK_MUL_S(o, ones, wo[5]);                      // (b_out, b_out)
#pragma unroll
    for (int i = 0; i < MLP_D; ++i)
        PK_FMA_S(o, h[i], wo[i]);
    *reinterpret_cast<f2*>(out + row0) = o;
}

extern "C" void kernel_launch(void* const* d_in, const int* in_sizes, int n_in,
                              void* d_out, int out_size, void* d_ws, size_t ws_size,
                              hipStream_t stream) {
    const float* x     = (const float*)d_in[0];
    const float* Ws    = (const float*)d_in[1];
    const float* bs    = (const float*)d_in[2];
    const float* W_out = (const float*)d_in[3];
    const float* b_out = (const float*)d_in[4];
    float* out = (float*)d_out;
    float* ws  = (float*)d_ws;   // needs (64*30+6)*2*4 = 15,408 B

    const int n = in_sizes[0] / MLP_D;  // batch rows (1048576)

    const int npairs = MLP_DEPTH * 30 + 6;
    MLP_prep_kernel<<<(npairs + 255) / 256, 256, 0, stream>>>(Ws, bs, W_out, b_out, ws);

    const int block = 256;
    const int threads_needed = (n + 1) / 2;
    const int grid = (threads_needed + block - 1) / block;
    MLP_89687507075104_kernel<<<grid, block, 0, stream>>>(
        x, (const unsigned long long*)ws, out, n);
}

// Round 6
// 126.828 us; speedup vs baseline: 1.0302x; 1.0302x over previous
//
#include <hip/hip_runtime.h>

// MLP: 64 × (Linear(5,5)+ReLU) then Linear(5,1), BATCH = 1048576 rows.
// fp32 VALU compute-bound. R6: v_pk_fma_f32 with OP_SEL broadcast of the
// weight half — no splat movs, no SGPR games.
//
// R2-R5 lesson: the compiler keeps wave-uniform weights in VGPRs (VMEM
// loads); SGPR-operand tricks cause readfirstlane (R5: +60 instr/layer),
// C++-level packing causes 2-mov splats (R3/R4). Fix: VOP3P op_sel_hi/
// op_sel modifiers make ONE 32-bit half of a weight VGPR pair feed BOTH
// halves of the packed FMA:
//   lo half:  v_pk_fma_f32 a, h, w, a op_sel_hi:[1,0,1]
//   hi half:  v_pk_fma_f32 a, h, w, a op_sel:[0,1,0] op_sel_hi:[1,1,1]
//   acc init: v_pk_mul_f32 a, 1.0, b  op_sel_hi:[0,0] (+hi variant)
// Weights prep'd into [64][32]-float layout (25 W + 5 b + 2 pad) so each
// layer is 8 aligned dwordx4 loads -> 16 f2 pairs, each pair feeding 2 FMAs.
// 4 rows/thread (2 f2 row-pairs): 70 VALU + 8 VMEM per layer per thread.

#define MLP_DEPTH 64
#define MLP_D 5

typedef float f2 __attribute__((ext_vector_type(2)));
typedef float f4 __attribute__((ext_vector_type(4)));

// acc += h * w.lo (both halves of h; w low half broadcast)
#define PK_FMA_LO(acc, hv, wv) \
    asm("v_pk_fma_f32 %0, %1, %2, %0 op_sel_hi:[1,0,1]" \
        : "+v"(acc) : "v"(hv), "v"(wv))
// acc += h * w.hi
#define PK_FMA_HI(acc, hv, wv) \
    asm("v_pk_fma_f32 %0, %1, %2, %0 op_sel:[0,1,0] op_sel_hi:[1,1,1]" \
        : "+v"(acc) : "v"(hv), "v"(wv))
// acc = (w.lo, w.lo)
#define PK_INIT_LO(acc, wv) \
    asm("v_pk_mul_f32 %0, 1.0, %1 op_sel_hi:[0,0]" \
        : "=v"(acc) : "v"(wv))
// acc = (w.hi, w.hi)
#define PK_INIT_HI(acc, wv) \
    asm("v_pk_mul_f32 %0, 1.0, %1 op_sel:[0,1] op_sel_hi:[0,1]" \
        : "=v"(acc) : "v"(wv))

// d_ws: [64][32] floats per layer (k<25: W[j*5+i] j-major; 25..29: b[j];
// 30,31: pad) then 8 floats: W_out[0..4], b_out, pad, pad. Total 2056 floats.
__global__ __launch_bounds__(256) void MLP_prep_kernel(
    const float* __restrict__ Ws, const float* __restrict__ bs,
    const float* __restrict__ W_out, const float* __restrict__ b_out,
    float* __restrict__ ws)
{
    const int idx = blockIdx.x * blockDim.x + threadIdx.x;
    if (idx < MLP_DEPTH * 32) {
        const int l = idx >> 5, k = idx & 31;
        float v = 0.0f;
        if (k < 25) v = Ws[l * 25 + k];
        else if (k < 30) v = bs[l * MLP_D + (k - 25)];
        ws[idx] = v;
    } else if (idx < MLP_DEPTH * 32 + 8) {
        const int k = idx - MLP_DEPTH * 32;
        float v = 0.0f;
        if (k < MLP_D) v = W_out[k];
        else if (k == MLP_D) v = b_out[0];
        ws[idx] = v;
    }
}

__global__ __launch_bounds__(256, 4) void MLP_89687507075104_kernel(
    const float* __restrict__ x,   // [n, 5]
    const f4* __restrict__ wq,     // prep'd weights, 8 float4 per layer
    float* __restrict__ out,       // [n]
    int n)
{
    const int t = blockIdx.x * blockDim.x + threadIdx.x;
    const long row0 = (long)t * 4;
    if (row0 >= n) return;

    // 20 contiguous floats = rows row0..row0+3 (80B, 16B-aligned).
    float f[20];
    const f4* xp = reinterpret_cast<const f4*>(x + row0 * MLP_D);
#pragma unroll
    for (int q = 0; q < 5; ++q) {
        const f4 v = xp[q];
        f[4 * q + 0] = v.x; f[4 * q + 1] = v.y;
        f[4 * q + 2] = v.z; f[4 * q + 3] = v.w;
    }
    // h[p][i] = (h_i of row 2p, h_i of row 2p+1)
    f2 h[2][MLP_D];
#pragma unroll
    for (int i = 0; i < MLP_D; ++i) {
        h[0][i] = (f2){ f[i],          f[MLP_D + i] };
        h[1][i] = (f2){ f[2*MLP_D+i],  f[3*MLP_D+i] };
    }

#pragma unroll
    for (int l = 0; l < MLP_DEPTH; ++l) {
        const f4* wp = wq + l * 8;  // wave-uniform address, const offsets
        f2 W[16];
#pragma unroll
        for (int m = 0; m < 8; ++m) {
            const f4 q = wp[m];
            W[2 * m + 0] = __builtin_shufflevector(q, q, 0, 1);
            W[2 * m + 1] = __builtin_shufflevector(q, q, 2, 3);
        }
        f2 a[2][MLP_D];
#pragma unroll
        for (int p = 0; p < 2; ++p) {
#pragma unroll
            for (int j = 0; j < MLP_D; ++j) {
                const int kb = 25 + j;  // bias slot
                if (kb & 1) { PK_INIT_HI(a[p][j], W[kb >> 1]); }
                else        { PK_INIT_LO(a[p][j], W[kb >> 1]); }
#pragma unroll
                for (int i = 0; i < MLP_D; ++i) {
                    const int k = j * MLP_D + i;
                    if (k & 1) { PK_FMA_HI(a[p][j], h[p][i], W[k >> 1]); }
                    else       { PK_FMA_LO(a[p][j], h[p][i], W[k >> 1]); }
                }
            }
        }
#pragma unroll
        for (int p = 0; p < 2; ++p)
#pragma unroll
            for (int j = 0; j < MLP_D; ++j)
                h[p][j] = __builtin_elementwise_max(a[p][j], (f2)0.0f);
    }

    // Output layer: Linear(5,1). Slot layout: k 0..4 = W_out, k 5 = b_out.
    const f4* wp = wq + MLP_DEPTH * 8;
    const f4 q0 = wp[0], q1 = wp[1];
    f2 WO[3];
    WO[0] = __builtin_shufflevector(q0, q0, 0, 1);
    WO[1] = __builtin_shufflevector(q0, q0, 2, 3);
    WO[2] = __builtin_shufflevector(q1, q1, 0, 1);
    f2 o[2];
#pragma unroll
    for (int p = 0; p < 2; ++p) {
        PK_INIT_HI(o[p], WO[2]);  // b_out at k=5 (hi half of WO[2])
#pragma unroll
        for (int i = 0; i < MLP_D; ++i) {
            if (i & 1) { PK_FMA_HI(o[p], h[p][i], WO[i >> 1]); }
            else       { PK_FMA_LO(o[p], h[p][i], WO[i >> 1]); }
        }
    }
    f4 ov;
    ov.x = o[0][0]; ov.y = o[0][1]; ov.z = o[1][0]; ov.w = o[1][1];
    *reinterpret_cast<f4*>(out + row0) = ov;
}

extern "C" void kernel_launch(void* const* d_in, const int* in_sizes, int n_in,
                              void* d_out, int out_size, void* d_ws, size_t ws_size,
                              hipStream_t stream) {
    const float* x     = (const float*)d_in[0];
    const float* Ws    = (const float*)d_in[1];
    const float* bs    = (const float*)d_in[2];
    const float* W_out = (const float*)d_in[3];
    const float* b_out = (const float*)d_in[4];
    float* out = (float*)d_out;
    float* ws  = (float*)d_ws;   // needs (64*32+8)*4 = 8224 B

    const int n = in_sizes[0] / MLP_D;  // batch rows (1048576)

    const int nprep = MLP_DEPTH * 32 + 8;
    MLP_prep_kernel<<<(nprep + 255) / 256, 256, 0, stream>>>(Ws, bs, W_out, b_out, ws);

    const int block = 256;
    const int threads_needed = (n + 3) / 4;
    const int grid = (threads_needed + block - 1) / block;
    MLP_89687507075104_kernel<<<grid, block, 0, stream>>>(
        x, reinterpret_cast<const f4*>(ws), out, n);
}

// Round 8
// 109.568 us; speedup vs baseline: 1.1925x; 1.1575x over previous
//
#include <hip/hip_runtime.h>

// MLP: 64 × (Linear(5,5)+ReLU) then Linear(5,1), BATCH = 1048576 rows.
// fp32 VALU compute-bound. R8: SCALAR fp32 + ALL WEIGHTS IN LDS.
//
// R2-R7 lesson: register-class games for cheap weights all fail (splats,
// readfirstlane, asm-island copies, allocator crash). R2's scalar version
// was clean EXCEPT ~26 extra VALU/row/layer of 64-bit global address
// arithmetic (weights span 16KB > 13-bit imm). Fix: stage the whole padded
// weight array (64×32 + 8 floats = 8.2KB) in LDS once per block — every
// ds_read offset is a 16-bit immediate from ONE base, zero address VALU,
// and same-address reads broadcast conflict-free. 8× ds_read_b128/layer.
//
// 4 rows/thread: per layer = 8 DS + 120 VALU (4×25 v_fma_f32, bias enters
// as the first fma's VOP3 addend; 4×5 v_max_f32) = 30 VALU/row — the
// scalar ideal. Grid 1024 blocks = 4 waves/SIMD; 20 independent fma chains
// give plenty of ILP. __launch_bounds__(256,4) = 128-VGPR budget (~75 used)
// so the compiler can prefetch next layer's ds_reads.

#define MLP_DEPTH 64
#define MLP_D 5
#define ROWS 4

// LDS layout: layer l at sw[l*32]: k<25 -> W[j*5+i] (k=j*5+i), 25..29 -> b[j],
// 30..31 pad. Then at sw[2048]: W_out[0..4], b_out, pad, pad. Total 2056.
#define LDS_N 2056

__global__ __launch_bounds__(256, 4) void MLP_89687507075104_kernel(
    const float* __restrict__ x,      // [n, 5]
    const float* __restrict__ Ws,     // [64, 5, 5]
    const float* __restrict__ bs,     // [64, 5]
    const float* __restrict__ W_out,  // [1, 5]
    const float* __restrict__ b_out,  // [1]
    float* __restrict__ out,          // [n]
    int n)
{
    __shared__ float sw[LDS_N];
    for (int idx = threadIdx.x; idx < LDS_N; idx += 256) {
        float v;
        if (idx < MLP_DEPTH * 32) {
            const int l = idx >> 5, k = idx & 31;
            v = (k < 25) ? Ws[l * 25 + k]
              : (k < 30) ? bs[l * MLP_D + (k - 25)]
              : 0.0f;
        } else {
            const int k = idx - MLP_DEPTH * 32;
            v = (k < MLP_D) ? W_out[k] : (k == MLP_D) ? b_out[0] : 0.0f;
        }
        sw[idx] = v;
    }
    __syncthreads();

    const int t = blockIdx.x * blockDim.x + threadIdx.x;
    const long row0 = (long)t * ROWS;
    if (row0 >= n) return;

    // rows row0..row0+3 = 20 contiguous floats (80 B, 16B-aligned).
    const float4* xp = reinterpret_cast<const float4*>(x + row0 * MLP_D);
    const float4 q0 = xp[0], q1 = xp[1], q2 = xp[2], q3 = xp[3], q4 = xp[4];
    float h[ROWS][MLP_D];
    h[0][0]=q0.x; h[0][1]=q0.y; h[0][2]=q0.z; h[0][3]=q0.w; h[0][4]=q1.x;
    h[1][0]=q1.y; h[1][1]=q1.z; h[1][2]=q1.w; h[1][3]=q2.x; h[1][4]=q2.y;
    h[2][0]=q2.z; h[2][1]=q2.w; h[2][2]=q3.x; h[2][3]=q3.y; h[2][4]=q3.z;
    h[3][0]=q3.w; h[3][1]=q4.x; h[3][2]=q4.y; h[3][3]=q4.z; h[3][4]=q4.w;

#pragma unroll
    for (int l = 0; l < MLP_DEPTH; ++l) {
        // 8× ds_read_b128, broadcast (all lanes same address), offsets are
        // 16-bit immediates off one base -> zero address VALU.
        const float4* wq = reinterpret_cast<const float4*>(&sw[l * 32]);
        float W[32];
#pragma unroll
        for (int m = 0; m < 8; ++m) {
            const float4 c = wq[m];
            W[4*m+0] = c.x; W[4*m+1] = c.y; W[4*m+2] = c.z; W[4*m+3] = c.w;
        }
        float a[ROWS][MLP_D];
#pragma unroll
        for (int r = 0; r < ROWS; ++r) {
#pragma unroll
            for (int j = 0; j < MLP_D; ++j) {
                // bias enters as the first fma's addend (VOP3) — no init mov
                float acc = fmaf(h[r][0], W[j * MLP_D + 0], W[25 + j]);
#pragma unroll
                for (int i = 1; i < MLP_D; ++i)
                    acc = fmaf(h[r][i], W[j * MLP_D + i], acc);
                a[r][j] = acc;
            }
        }
#pragma unroll
        for (int r = 0; r < ROWS; ++r)
#pragma unroll
            for (int j = 0; j < MLP_D; ++j)
                h[r][j] = fmaxf(a[r][j], 0.0f);
    }

    // Output layer: Linear(5,1).
    const float4* oq = reinterpret_cast<const float4*>(&sw[MLP_DEPTH * 32]);
    const float4 c0 = oq[0], c1 = oq[1];
    const float wo0 = c0.x, wo1 = c0.y, wo2 = c0.z, wo3 = c0.w;
    const float wo4 = c1.x, bo = c1.y;
    float4 ov;
    float o[ROWS];
#pragma unroll
    for (int r = 0; r < ROWS; ++r) {
        float acc = fmaf(h[r][0], wo0, bo);
        acc = fmaf(h[r][1], wo1, acc);
        acc = fmaf(h[r][2], wo2, acc);
        acc = fmaf(h[r][3], wo3, acc);
        acc = fmaf(h[r][4], wo4, acc);
        o[r] = acc;
    }
    ov.x = o[0]; ov.y = o[1]; ov.z = o[2]; ov.w = o[3];
    *reinterpret_cast<float4*>(out + row0) = ov;
}

extern "C" void kernel_launch(void* const* d_in, const int* in_sizes, int n_in,
                              void* d_out, int out_size, void* d_ws, size_t ws_size,
                              hipStream_t stream) {
    const float* x     = (const float*)d_in[0];
    const float* Ws    = (const float*)d_in[1];
    const float* bs    = (const float*)d_in[2];
    const float* W_out = (const float*)d_in[3];
    const float* b_out = (const float*)d_in[4];
    float* out = (float*)d_out;

    const int n = in_sizes[0] / MLP_D;  // batch rows (1048576)
    const int block = 256;
    const int threads_needed = (n + ROWS - 1) / ROWS;
    const int grid = (threads_needed + block - 1) / block;  // 1024
    MLP_89687507075104_kernel<<<grid, block, 0, stream>>>(
        x, Ws, bs, W_out, b_out, out, n);
}